// Round 11
// baseline (1161.072 us; speedup 1.0000x reference)
//
#include <hip/hip_runtime.h>
#include <hip/hip_bf16.h>

typedef __bf16 bf16;
typedef __attribute__((ext_vector_type(8))) bf16 bf16x8;
typedef __attribute__((ext_vector_type(4))) float f32x4;

constexpr int B_   = 16;
constexpr int E_   = 400;
constexpr int R_   = 624;
constexpr int N_   = 1024;
constexpr int HSZ_ = 512;
constexpr int DFF_ = 2048;
constexpr int M_   = B_ * N_;

// ---------------------------------------------------------------------------
__global__ __launch_bounds__(256) void transpose_f32_bf16(const float* __restrict__ in,
                                                          bf16* __restrict__ out,
                                                          int rows, int cols) {
    __shared__ float tile[32][33];
    int c0 = blockIdx.x * 32, r0 = blockIdx.y * 32;
    int tx = threadIdx.x, ty = threadIdx.y;   // 32 x 8
    #pragma unroll
    for (int i = 0; i < 32; i += 8)
        tile[ty + i][tx] = in[(size_t)(r0 + ty + i) * cols + (c0 + tx)];
    __syncthreads();
    #pragma unroll
    for (int i = 0; i < 32; i += 8)
        out[(size_t)(c0 + ty + i) * rows + (r0 + tx)] = (bf16)tile[tx][ty + i];
}

// ---------------------------------------------------------------------------
__global__ __launch_bounds__(256) void pack_adj(const int* __restrict__ adj,
                                                unsigned* __restrict__ adjw) {
    int gid  = blockIdx.x * 4 + (threadIdx.x >> 6);
    int lane = threadIdx.x & 63;
    int w64  = gid & 15;
    int bn   = gid >> 4;
    int v = adj[(size_t)bn * N_ + w64 * 64 + lane];
    unsigned long long mask = __ballot(v != 0);
    if (lane == 0)  adjw[bn * 32 + w64 * 2]     = (unsigned)mask;
    if (lane == 32) adjw[bn * 32 + w64 * 2 + 1] = (unsigned)(mask >> 32);
}

// ---------------------------------------------------------------------------
__global__ __launch_bounds__(256) void build_x(const float* __restrict__ ents,
                                               const int* __restrict__ rels,
                                               const float* __restrict__ renc,
                                               bf16* __restrict__ x) {
    int idx  = blockIdx.x * 256 + threadIdx.x;
    int col8 = (idx & 63) * 8;
    int row  = idx >> 6;
    int b = row >> 10, n = row & 1023;
    const float* src;
    if (n < E_) src = ents + ((size_t)(b * E_ + n)) * HSZ_ + col8;
    else {
        int rt = rels[b * R_ + (n - E_)];
        src = renc + (size_t)rt * HSZ_ + col8;
    }
    float4 a = *(const float4*)src;
    float4 c = *(const float4*)(src + 4);
    bf16x8 v;
    v[0] = (bf16)a.x; v[1] = (bf16)a.y; v[2] = (bf16)a.z; v[3] = (bf16)a.w;
    v[4] = (bf16)c.x; v[5] = (bf16)c.y; v[6] = (bf16)c.z; v[7] = (bf16)c.w;
    *(bf16x8*)(x + (size_t)row * HSZ_ + col8) = v;
}

// ---------------------------------------------------------------------------
// GEMM: C(M x Nn) = A(M x Kk) @ Bt(Nn x Kk)^T   128x128 tile, 4 waves (2x2),
// 4x4 16x16x32 MFMA tiles/wave. Staging via global_load_lds width=16
// (wave-uniform LDS base + lane*16; tiles UNPADDED per m104/m108 contract).
template <int MODE>
__global__ __launch_bounds__(256) void gemm_bt(const bf16* __restrict__ A,
                                               const bf16* __restrict__ Bt,
                                               const float* __restrict__ biasF,
                                               const float* __restrict__ alphaF,
                                               const bf16* __restrict__ extraB,
                                               bf16* __restrict__ outB,
                                               float* __restrict__ outF,
                                               int Nn, int Kk) {
    __shared__ bf16 As[128 * 64];
    __shared__ bf16 Bs[128 * 64];
    int n0 = blockIdx.x * 128, m0 = blockIdx.y * 128;
    int t = threadIdx.x;
    int w = t >> 6, lane = t & 63, r = lane & 15, quad = lane >> 4;
    int wm = w >> 1, wn = w & 1;
    int lrow = lane >> 3;            // 0..7
    int lcol = (lane & 7) * 8;       // 0,8,..,56
    f32x4 acc[4][4];
    #pragma unroll
    for (int mt = 0; mt < 4; mt++)
        #pragma unroll
        for (int nt = 0; nt < 4; nt++) acc[mt][nt] = (f32x4){0.f, 0.f, 0.f, 0.f};

    for (int k0 = 0; k0 < Kk; k0 += 64) {
        #pragma unroll
        for (int s = 0; s < 4; s++) {
            int row = w * 32 + s * 8 + lrow;     // tile row this lane fetches
            __builtin_amdgcn_global_load_lds(
                (const __attribute__((address_space(1))) unsigned int*)
                    &A[(size_t)(m0 + row) * Kk + k0 + lcol],
                (__attribute__((address_space(3))) unsigned int*)
                    &As[(w * 32 + s * 8) * 64],
                16, 0, 0);
            __builtin_amdgcn_global_load_lds(
                (const __attribute__((address_space(1))) unsigned int*)
                    &Bt[(size_t)(n0 + row) * Kk + k0 + lcol],
                (__attribute__((address_space(3))) unsigned int*)
                    &Bs[(w * 32 + s * 8) * 64],
                16, 0, 0);
        }
        __syncthreads();
        #pragma unroll
        for (int kk = 0; kk < 64; kk += 32) {
            bf16x8 af[4], bfr[4];
            #pragma unroll
            for (int mt = 0; mt < 4; mt++)
                af[mt] = *(const bf16x8*)&As[(wm * 64 + mt * 16 + r) * 64 + kk + quad * 8];
            #pragma unroll
            for (int nt = 0; nt < 4; nt++)
                bfr[nt] = *(const bf16x8*)&Bs[(wn * 64 + nt * 16 + r) * 64 + kk + quad * 8];
            #pragma unroll
            for (int mt = 0; mt < 4; mt++)
                #pragma unroll
                for (int nt = 0; nt < 4; nt++)
                    acc[mt][nt] = __builtin_amdgcn_mfma_f32_16x16x32_bf16(af[mt], bfr[nt], acc[mt][nt], 0, 0, 0);
        }
        __syncthreads();
    }
    #pragma unroll
    for (int mt = 0; mt < 4; mt++) {
        #pragma unroll
        for (int nt = 0; nt < 4; nt++) {
            #pragma unroll
            for (int i = 0; i < 4; i++) {
                int rg = m0 + wm * 64 + mt * 16 + quad * 4 + i;
                int cg = n0 + wn * 64 + nt * 16 + r;
                float v = acc[mt][nt][i];
                if (MODE == 0) {
                    outB[(size_t)rg * Nn + cg] = (bf16)v;
                } else if (MODE == 1) {
                    int bb = rg >> 10, n = rg & 1023;
                    outB[(size_t)(bb * HSZ_ + cg) * N_ + n] = (bf16)v;
                } else if (MODE == 2) {
                    v += biasF[cg];
                    float a = alphaF[cg];
                    v = v > 0.f ? v : a * v;
                    outB[(size_t)rg * Nn + cg] = (bf16)v;
                } else {
                    v += biasF[cg] + (float)extraB[(size_t)rg * Nn + cg];
                    outF[(size_t)rg * Nn + cg] = v;
                }
            }
        }
    }
}

// ---------------------------------------------------------------------------
// Fused MFMA attention v4: BARRIER-FREE. Each wave fully owns (b,h,16 q-rows):
// 32 keys/iter QK^T -> fixed-shift exp -> within-wave LDS roundtrip (lgkmcnt
// only, no __syncthreads) -> PV over all 128 dims. 4 waves/block for
// occupancy; XCD-swizzled grid so each (b,h) group's K/Vt stays L2-resident.
__global__ __launch_bounds__(256) void attn_fused(const bf16* __restrict__ Q,
                                                  const bf16* __restrict__ K,
                                                  const bf16* __restrict__ Vt,
                                                  const unsigned* __restrict__ adjw,
                                                  const bf16* __restrict__ xb,
                                                  float* __restrict__ tpre) {
    int blk = blockIdx.x;
    // blk = gr + 8*(tq + 16*gq): group g = gq*8+gr (b*4+h), tile-quad tq.
    int gr = blk & 7;
    int tq = (blk >> 3) & 15;
    int gq = blk >> 7;
    int g = gq * 8 + gr;
    int b = g >> 2, h = g & 3;

    int tid = threadIdx.x;
    int w = tid >> 6, lane = tid & 63;
    int r = lane & 15, quad = lane >> 4;
    int n0 = (tq * 4 + w) * 16;      // this wave's 16 q-rows

    __shared__ bf16 plds[4][16][36];   // per-wave region; pad 36 ok (plain ds ops)

    bf16x8 qf[4];
    const bf16* qbase = Q + ((size_t)(b * N_ + n0 + r)) * HSZ_ + h * 128;
    #pragma unroll
    for (int kc = 0; kc < 4; kc++) qf[kc] = *(const bf16x8*)(qbase + kc * 32 + quad * 8);

    f32x4 accv[8];
    #pragma unroll
    for (int dt = 0; dt < 8; dt++) accv[dt] = (f32x4){0.f, 0.f, 0.f, 0.f};
    float tl[4] = {0.f, 0.f, 0.f, 0.f};
    const float scale = 0.04419417382415922f;   // 1/sqrt(512)
    const float SHIFT = 12.0f;

    for (int it = 0; it < 32; it++) {
        f32x4 c0 = {0,0,0,0}, c1 = {0,0,0,0};
        const bf16* kb0 = K + ((size_t)(b * N_ + it * 32 + r)) * HSZ_ + h * 128;
        const bf16* kb1 = kb0 + 16 * HSZ_;
        #pragma unroll
        for (int kc = 0; kc < 4; kc++) {
            bf16x8 k0f = *(const bf16x8*)(kb0 + kc * 32 + quad * 8);
            bf16x8 k1f = *(const bf16x8*)(kb1 + kc * 32 + quad * 8);
            c0 = __builtin_amdgcn_mfma_f32_16x16x32_bf16(qf[kc], k0f, c0, 0, 0, 0);
            c1 = __builtin_amdgcn_mfma_f32_16x16x32_bf16(qf[kc], k1f, c1, 0, 0, 0);
        }
        #pragma unroll
        for (int i = 0; i < 4; i++) {
            int row_g = n0 + quad * 4 + i;
            unsigned wb = adjw[((size_t)(b << 10) + row_g) * 32 + it];
            float p0 = ((wb >> r) & 1u)        ? __expf(c0[i] * scale - SHIFT) : 0.f;
            float p1 = ((wb >> (16 + r)) & 1u) ? __expf(c1[i] * scale - SHIFT) : 0.f;
            tl[i] += p0 + p1;
            plds[w][quad * 4 + i][r]      = (bf16)p0;
            plds[w][quad * 4 + i][16 + r] = (bf16)p1;
        }
        // within-wave ds_write -> ds_read: compiler inserts lgkmcnt; no barrier.
        bf16x8 pf = *(const bf16x8*)&plds[w][r][quad * 8];
        #pragma unroll
        for (int dt = 0; dt < 8; dt++) {
            const bf16* vb = Vt + ((size_t)(b * HSZ_ + h * 128 + dt * 16 + r)) * N_
                               + it * 32 + quad * 8;
            bf16x8 vf = *(const bf16x8*)vb;
            accv[dt] = __builtin_amdgcn_mfma_f32_16x16x32_bf16(pf, vf, accv[dt], 0, 0, 0);
        }
    }
    #pragma unroll
    for (int i = 0; i < 4; i++) {
        float l = tl[i];
        #pragma unroll
        for (int d = 1; d < 16; d <<= 1) l += __shfl_xor(l, d, 64);
        float inv_l = 1.0f / fmaxf(l, 1e-30f);
        #pragma unroll
        for (int dt = 0; dt < 8; dt++) {
            int row = n0 + quad * 4 + i;
            int col = h * 128 + dt * 16 + r;
            size_t idx = ((size_t)(b * N_ + row)) * HSZ_ + col;
            tpre[idx] = accv[dt][i] * inv_l + (float)xb[idx];
        }
    }
}

// ---------------------------------------------------------------------------
__global__ __launch_bounds__(64) void lnorm_k(const float* __restrict__ in,
                                              const float* __restrict__ sc,
                                              const float* __restrict__ bi,
                                              bf16* __restrict__ out) {
    int row = blockIdx.x;
    int lane = threadIdx.x;
    const float* rp = in + (size_t)row * HSZ_;
    float4 a = *(const float4*)(rp + lane * 4);
    float4 b = *(const float4*)(rp + 256 + lane * 4);
    float sum = a.x + a.y + a.z + a.w + b.x + b.y + b.z + b.w;
    float sq  = a.x*a.x + a.y*a.y + a.z*a.z + a.w*a.w
              + b.x*b.x + b.y*b.y + b.z*b.z + b.w*b.w;
    #pragma unroll
    for (int d = 1; d < 64; d <<= 1) {
        sum += __shfl_xor(sum, d, 64);
        sq  += __shfl_xor(sq,  d, 64);
    }
    float mu = sum * (1.0f / HSZ_);
    float varv = fmaxf(sq * (1.0f / HSZ_) - mu * mu, 0.f);
    float rs = rsqrtf(varv + 1e-5f);
    bf16* op = out + (size_t)row * HSZ_;
    int c0 = lane * 4;
    float va[4] = {a.x, a.y, a.z, a.w}, vb[4] = {b.x, b.y, b.z, b.w};
    #pragma unroll
    for (int k = 0; k < 4; k++) {
        op[c0 + k]       = (bf16)(((va[k] - mu) * rs) * sc[c0 + k] + bi[c0 + k]);
        op[c0 + 256 + k] = (bf16)(((vb[k] - mu) * rs) * sc[c0 + 256 + k] + bi[c0 + 256 + k]);
    }
}

// ---------------------------------------------------------------------------
__global__ __launch_bounds__(256) void write_out(const bf16* __restrict__ x,
                                                 float* __restrict__ out) {
    size_t tid = (size_t)blockIdx.x * 256 + threadIdx.x;
    if (tid < (size_t)B_ * HSZ_) {
        int b = (int)(tid >> 9), c = (int)(tid & 511);
        out[tid] = (float)x[((size_t)(b * N_ + E_)) * HSZ_ + c];
    } else if (tid < (size_t)B_ * HSZ_ + (size_t)B_ * N_ * HSZ_) {
        out[tid] = (float)x[tid - B_ * HSZ_];
    } else {
        out[tid] = 1.0f;
    }
}

// ---------------------------------------------------------------------------
extern "C" void kernel_launch(void* const* d_in, const int* in_sizes, int n_in,
                              void* d_out, int out_size, void* d_ws, size_t ws_size,
                              hipStream_t stream) {
    const float* ents = (const float*)d_in[0];
    const int*   rels = (const int*)d_in[1];
    const int*   adj  = (const int*)d_in[2];
    const float* renc = (const float*)d_in[3];
    const float* Wq   = (const float*)d_in[4];
    const float* Wk   = (const float*)d_in[5];
    const float* Wv   = (const float*)d_in[6];
    const float* l1w  = (const float*)d_in[7];
    const float* l1b  = (const float*)d_in[8];
    const float* l2w  = (const float*)d_in[9];
    const float* l2b  = (const float*)d_in[10];
    const float* ln1s = (const float*)d_in[11];
    const float* ln1b = (const float*)d_in[12];
    const float* ln2s = (const float*)d_in[13];
    const float* ln2b = (const float*)d_in[14];
    const float* pa   = (const float*)d_in[15];

    char* ws = (char*)d_ws;
    size_t o = 0;
    auto alloc = [&](size_t bytes) { void* p = ws + o; o += bytes; return p; };
    bf16*     WqT    = (bf16*)alloc(1048576);
    bf16*     WkT    = (bf16*)alloc(1048576);
    bf16*     WvT    = (bf16*)alloc(1048576);
    bf16*     L1T    = (bf16*)alloc(4194304);
    bf16*     L2T    = (bf16*)alloc(4194304);
    unsigned* adjw   = (unsigned*)alloc(2097152);
    bf16*     xb     = (bf16*)alloc(16777216);
    bf16*     Qb     = (bf16*)alloc(16777216);
    bf16*     Kb     = (bf16*)alloc(16777216);
    bf16*     Vt     = (bf16*)alloc(16777216);
    bf16*     tb     = (bf16*)alloc(16777216);
    bf16*     hb     = (bf16*)alloc(67108864);
    float*    f32buf = (float*)alloc(33554432);
    if (o > ws_size) return;

    dim3 t32(32, 8);
    for (int j = 0; j < 2; j++) {
        transpose_f32_bf16<<<dim3(16, 16), t32, 0, stream>>>(Wq  + j * 262144,  WqT + j * 262144, 512, 512);
        transpose_f32_bf16<<<dim3(16, 16), t32, 0, stream>>>(Wk  + j * 262144,  WkT + j * 262144, 512, 512);
        transpose_f32_bf16<<<dim3(16, 16), t32, 0, stream>>>(Wv  + j * 262144,  WvT + j * 262144, 512, 512);
        transpose_f32_bf16<<<dim3(64, 16), t32, 0, stream>>>(l1w + j * 1048576, L1T + j * 1048576, 512, 2048);
        transpose_f32_bf16<<<dim3(16, 64), t32, 0, stream>>>(l2w + j * 1048576, L2T + j * 1048576, 2048, 512);
    }
    pack_adj<<<65536, 256, 0, stream>>>(adj, adjw);
    build_x<<<4096, 256, 0, stream>>>(ents, rels, renc, xb);

    for (int j = 0; j < 2; j++) {
        gemm_bt<0><<<dim3(4, 128), 256, 0, stream>>>(xb, WqT + j * 262144, nullptr, nullptr, nullptr, Qb, nullptr, 512, 512);
        gemm_bt<0><<<dim3(4, 128), 256, 0, stream>>>(xb, WkT + j * 262144, nullptr, nullptr, nullptr, Kb, nullptr, 512, 512);
        gemm_bt<1><<<dim3(4, 128), 256, 0, stream>>>(xb, WvT + j * 262144, nullptr, nullptr, nullptr, Vt, nullptr, 512, 512);
        attn_fused<<<1024, 256, 0, stream>>>(Qb, Kb, Vt, adjw, xb, f32buf);
        lnorm_k<<<16384, 64, 0, stream>>>(f32buf, ln1s + j * 512, ln1b + j * 512, tb);
        gemm_bt<2><<<dim3(16, 128), 256, 0, stream>>>(tb, L1T + j * 1048576, l1b + j * 2048, pa + j * 2048, nullptr, hb, nullptr, 2048, 512);
        gemm_bt<3><<<dim3(4, 128), 256, 0, stream>>>(hb, L2T + j * 1048576, l2b + j * 512, nullptr, tb, nullptr, f32buf, 512, 2048);
        lnorm_k<<<16384, 64, 0, stream>>>(f32buf, ln2s + j * 512, ln2b + j * 512, xb);
    }
    write_out<<<32864, 256, 0, stream>>>(xb, (float*)d_out);
}

// Round 14
// 843.609 us; speedup vs baseline: 1.3763x; 1.3763x over previous
//
#include <hip/hip_runtime.h>
#include <hip/hip_bf16.h>

typedef __bf16 bf16;
typedef __attribute__((ext_vector_type(8))) bf16 bf16x8;
typedef __attribute__((ext_vector_type(4))) float f32x4;

constexpr int B_   = 16;
constexpr int E_   = 400;
constexpr int R_   = 624;
constexpr int N_   = 1024;
constexpr int HSZ_ = 512;
constexpr int DFF_ = 2048;
constexpr int M_   = B_ * N_;

// ---------------------------------------------------------------------------
__global__ __launch_bounds__(256) void transpose_f32_bf16(const float* __restrict__ in,
                                                          bf16* __restrict__ out,
                                                          int rows, int cols) {
    __shared__ float tile[32][33];
    int c0 = blockIdx.x * 32, r0 = blockIdx.y * 32;
    int tx = threadIdx.x, ty = threadIdx.y;   // 32 x 8
    #pragma unroll
    for (int i = 0; i < 32; i += 8)
        tile[ty + i][tx] = in[(size_t)(r0 + ty + i) * cols + (c0 + tx)];
    __syncthreads();
    #pragma unroll
    for (int i = 0; i < 32; i += 8)
        out[(size_t)(c0 + ty + i) * rows + (r0 + tx)] = (bf16)tile[tx][ty + i];
}

// ---------------------------------------------------------------------------
__global__ __launch_bounds__(256) void pack_adj(const int* __restrict__ adj,
                                                unsigned* __restrict__ adjw) {
    int gid  = blockIdx.x * 4 + (threadIdx.x >> 6);
    int lane = threadIdx.x & 63;
    int w64  = gid & 15;
    int bn   = gid >> 4;
    int v = adj[(size_t)bn * N_ + w64 * 64 + lane];
    unsigned long long mask = __ballot(v != 0);
    if (lane == 0)  adjw[bn * 32 + w64 * 2]     = (unsigned)mask;
    if (lane == 32) adjw[bn * 32 + w64 * 2 + 1] = (unsigned)(mask >> 32);
}

// ---------------------------------------------------------------------------
__global__ __launch_bounds__(256) void build_x(const float* __restrict__ ents,
                                               const int* __restrict__ rels,
                                               const float* __restrict__ renc,
                                               bf16* __restrict__ x) {
    int idx  = blockIdx.x * 256 + threadIdx.x;
    int col8 = (idx & 63) * 8;
    int row  = idx >> 6;
    int b = row >> 10, n = row & 1023;
    const float* src;
    if (n < E_) src = ents + ((size_t)(b * E_ + n)) * HSZ_ + col8;
    else {
        int rt = rels[b * R_ + (n - E_)];
        src = renc + (size_t)rt * HSZ_ + col8;
    }
    float4 a = *(const float4*)src;
    float4 c = *(const float4*)(src + 4);
    bf16x8 v;
    v[0] = (bf16)a.x; v[1] = (bf16)a.y; v[2] = (bf16)a.z; v[3] = (bf16)a.w;
    v[4] = (bf16)c.x; v[5] = (bf16)c.y; v[6] = (bf16)c.z; v[7] = (bf16)c.w;
    *(bf16x8*)(x + (size_t)row * HSZ_ + col8) = v;
}

// ---------------------------------------------------------------------------
// GEMM (R10-proven): C(M x Nn) = A(M x Kk) @ Bt(Nn x Kk)^T, 128x128 tile,
// 4 waves (2x2), 4x4 16x16x32 MFMA tiles/wave, padded LDS staging.
template <int MODE>
__global__ __launch_bounds__(256) void gemm_bt(const bf16* __restrict__ A,
                                               const bf16* __restrict__ Bt,
                                               const float* __restrict__ biasF,
                                               const float* __restrict__ alphaF,
                                               const bf16* __restrict__ extraB,
                                               bf16* __restrict__ outB,
                                               float* __restrict__ outF,
                                               int Nn, int Kk) {
    __shared__ bf16 As[128][72];
    __shared__ bf16 Bs[128][72];
    int n0 = blockIdx.x * 128, m0 = blockIdx.y * 128;
    int t = threadIdx.x;
    int w = t >> 6, lane = t & 63, r = lane & 15, quad = lane >> 4;
    int wm = w >> 1, wn = w & 1;
    f32x4 acc[4][4];
    #pragma unroll
    for (int mt = 0; mt < 4; mt++)
        #pragma unroll
        for (int nt = 0; nt < 4; nt++) acc[mt][nt] = (f32x4){0.f, 0.f, 0.f, 0.f};

    for (int k0 = 0; k0 < Kk; k0 += 64) {
        #pragma unroll
        for (int i = 0; i < 4; i++) {
            int v = t + i * 256;
            int row = v >> 3, c8 = (v & 7) * 8;
            *(uint4*)&As[row][c8] = *(const uint4*)&A[(size_t)(m0 + row) * Kk + k0 + c8];
            *(uint4*)&Bs[row][c8] = *(const uint4*)&Bt[(size_t)(n0 + row) * Kk + k0 + c8];
        }
        __syncthreads();
        #pragma unroll
        for (int kk = 0; kk < 64; kk += 32) {
            bf16x8 af[4], bfr[4];
            #pragma unroll
            for (int mt = 0; mt < 4; mt++)
                af[mt] = *(const bf16x8*)&As[wm * 64 + mt * 16 + r][kk + quad * 8];
            #pragma unroll
            for (int nt = 0; nt < 4; nt++)
                bfr[nt] = *(const bf16x8*)&Bs[wn * 64 + nt * 16 + r][kk + quad * 8];
            #pragma unroll
            for (int mt = 0; mt < 4; mt++)
                #pragma unroll
                for (int nt = 0; nt < 4; nt++)
                    acc[mt][nt] = __builtin_amdgcn_mfma_f32_16x16x32_bf16(af[mt], bfr[nt], acc[mt][nt], 0, 0, 0);
        }
        __syncthreads();
    }
    #pragma unroll
    for (int mt = 0; mt < 4; mt++) {
        #pragma unroll
        for (int nt = 0; nt < 4; nt++) {
            #pragma unroll
            for (int i = 0; i < 4; i++) {
                int rg = m0 + wm * 64 + mt * 16 + quad * 4 + i;
                int cg = n0 + wn * 64 + nt * 16 + r;
                float v = acc[mt][nt][i];
                if (MODE == 0) {
                    outB[(size_t)rg * Nn + cg] = (bf16)v;
                } else if (MODE == 1) {
                    int bb = rg >> 10, n = rg & 1023;
                    outB[(size_t)(bb * HSZ_ + cg) * N_ + n] = (bf16)v;
                } else if (MODE == 2) {
                    v += biasF[cg];
                    float a = alphaF[cg];
                    v = v > 0.f ? v : a * v;
                    outB[(size_t)rg * Nn + cg] = (bf16)v;
                } else {
                    v += biasF[cg] + (float)extraB[(size_t)rg * Nn + cg];
                    outF[(size_t)rg * Nn + cg] = v;
                }
            }
        }
    }
}

// ---------------------------------------------------------------------------
// Fused MFMA attention v6: REUSE-BLOCKED. Block = (b, h, 64 q-rows), 4 waves,
// wave w owns q-rows n0+w*16 end-to-end (R11-proven dataflow, no cross-wave
// combine). Per 64-key iteration the block stages K-tile (64x128) and V-tile
// (128x64) into LDS via global_load_lds (m97 pattern) — cuts L2/L3 traffic
// 4x vs 16-row blocks (2 GB -> 512 MB, the R10 wall). Fixed-shift softmax.
// Barriers only guard the shared K/V tiles + P visibility (R10-style, safe).
__global__ __launch_bounds__(256) void attn_fused(const bf16* __restrict__ Q,
                                                  const bf16* __restrict__ K,
                                                  const bf16* __restrict__ Vt,
                                                  const unsigned* __restrict__ adjw,
                                                  const bf16* __restrict__ xb,
                                                  float* __restrict__ tpre) {
    int blk = blockIdx.x;            // g*16 + qb, g = b*4 + h
    int qb = blk & 15;
    int g  = blk >> 4;
    int b = g >> 2, h = g & 3;

    int tid = threadIdx.x;
    int w = tid >> 6, lane = tid & 63;
    int r = lane & 15, quad = lane >> 4;
    int n0 = qb * 64 + w * 16;       // this wave's 16 q-rows

    __shared__ bf16 Ks[64 * 128];    // [key][dim]  16 KB, unpadded (glds)
    __shared__ bf16 Vs[128 * 64];    // [dim][key]  16 KB, unpadded (glds)
    __shared__ bf16 plds[4][16][68]; // per-wave P tile, padded (plain ds)

    bf16x8 qf[4];
    const bf16* qbase = Q + ((size_t)(b * N_ + n0 + r)) * HSZ_ + h * 128;
    #pragma unroll
    for (int kc = 0; kc < 4; kc++) qf[kc] = *(const bf16x8*)(qbase + kc * 32 + quad * 8);

    f32x4 accv[8];
    #pragma unroll
    for (int dt = 0; dt < 8; dt++) accv[dt] = (f32x4){0.f, 0.f, 0.f, 0.f};
    float tl[4] = {0.f, 0.f, 0.f, 0.f};
    const float scale = 0.04419417382415922f;   // 1/sqrt(512)
    const float SHIFT = 12.0f;

    for (int it = 0; it < 16; it++) {
        int key0 = it * 64;
        __syncthreads();   // all waves done reading Ks/Vs from prev iter
        // stage K rows [w*16, w*16+16): lane l -> row +(l>>4), chunk (l&15)
        #pragma unroll
        for (int s = 0; s < 4; s++) {
            int krow = w * 16 + s * 4 + (lane >> 4);
            __builtin_amdgcn_global_load_lds(
                (const __attribute__((address_space(1))) unsigned int*)
                    &K[((size_t)(b * N_ + key0 + krow)) * HSZ_ + h * 128 + (lane & 15) * 8],
                (__attribute__((address_space(3))) unsigned int*)
                    &Ks[(w * 16 + s * 4) * 128],
                16, 0, 0);
        }
        // stage V dims [w*32, w*32+32): lane l -> row +(l>>3), chunk (l&7)
        #pragma unroll
        for (int s = 0; s < 4; s++) {
            int vrow = w * 32 + s * 8 + (lane >> 3);
            __builtin_amdgcn_global_load_lds(
                (const __attribute__((address_space(1))) unsigned int*)
                    &Vt[((size_t)(b * HSZ_ + h * 128 + vrow)) * N_ + key0 + (lane & 7) * 8],
                (__attribute__((address_space(3))) unsigned int*)
                    &Vs[(w * 32 + s * 8) * 64],
                16, 0, 0);
        }
        __syncthreads();   // staging complete (vmcnt drained by barrier)

        // QK^T: 4 groups of 16 keys from LDS
        f32x4 cg[4];
        #pragma unroll
        for (int gk = 0; gk < 4; gk++) cg[gk] = (f32x4){0.f, 0.f, 0.f, 0.f};
        #pragma unroll
        for (int gk = 0; gk < 4; gk++)
            #pragma unroll
            for (int kc = 0; kc < 4; kc++) {
                bf16x8 kf = *(const bf16x8*)&Ks[(gk * 16 + r) * 128 + kc * 32 + quad * 8];
                cg[gk] = __builtin_amdgcn_mfma_f32_16x16x32_bf16(qf[kc], kf, cg[gk], 0, 0, 0);
            }
        // mask + exp -> plds + tl
        #pragma unroll
        for (int i = 0; i < 4; i++) {
            int row_g = n0 + quad * 4 + i;
            const unsigned* aw = &adjw[((size_t)(b << 10) + row_g) * 32 + it * 2];
            unsigned wb0 = aw[0], wb1 = aw[1];
            float p0 = ((wb0 >> r) & 1u)        ? __expf(cg[0][i] * scale - SHIFT) : 0.f;
            float p1 = ((wb0 >> (16 + r)) & 1u) ? __expf(cg[1][i] * scale - SHIFT) : 0.f;
            float p2 = ((wb1 >> r) & 1u)        ? __expf(cg[2][i] * scale - SHIFT) : 0.f;
            float p3 = ((wb1 >> (16 + r)) & 1u) ? __expf(cg[3][i] * scale - SHIFT) : 0.f;
            tl[i] += p0 + p1 + p2 + p3;
            plds[w][quad * 4 + i][r]      = (bf16)p0;
            plds[w][quad * 4 + i][16 + r] = (bf16)p1;
            plds[w][quad * 4 + i][32 + r] = (bf16)p2;
            plds[w][quad * 4 + i][48 + r] = (bf16)p3;
        }
        __syncthreads();   // P visible (block-wide barrier: proven-safe path)

        // PV: P (A-op, k=64 keys in 2 chunks) x Vs (B-op) for all 128 dims
        bf16x8 pf0 = *(const bf16x8*)&plds[w][r][quad * 8];
        bf16x8 pf1 = *(const bf16x8*)&plds[w][r][32 + quad * 8];
        #pragma unroll
        for (int dt = 0; dt < 8; dt++) {
            bf16x8 v0 = *(const bf16x8*)&Vs[(dt * 16 + r) * 64 + quad * 8];
            bf16x8 v1 = *(const bf16x8*)&Vs[(dt * 16 + r) * 64 + 32 + quad * 8];
            accv[dt] = __builtin_amdgcn_mfma_f32_16x16x32_bf16(pf0, v0, accv[dt], 0, 0, 0);
            accv[dt] = __builtin_amdgcn_mfma_f32_16x16x32_bf16(pf1, v1, accv[dt], 0, 0, 0);
        }
    }
    // per-wave epilogue (R11-proven)
    #pragma unroll
    for (int i = 0; i < 4; i++) {
        float l = tl[i];
        #pragma unroll
        for (int d = 1; d < 16; d <<= 1) l += __shfl_xor(l, d, 64);
        float inv_l = 1.0f / fmaxf(l, 1e-30f);
        #pragma unroll
        for (int dt = 0; dt < 8; dt++) {
            int row = n0 + quad * 4 + i;
            int col = h * 128 + dt * 16 + r;
            size_t idx = ((size_t)(b * N_ + row)) * HSZ_ + col;
            tpre[idx] = accv[dt][i] * inv_l + (float)xb[idx];
        }
    }
}

// ---------------------------------------------------------------------------
__global__ __launch_bounds__(64) void lnorm_k(const float* __restrict__ in,
                                              const float* __restrict__ sc,
                                              const float* __restrict__ bi,
                                              bf16* __restrict__ out) {
    int row = blockIdx.x;
    int lane = threadIdx.x;
    const float* rp = in + (size_t)row * HSZ_;
    float4 a = *(const float4*)(rp + lane * 4);
    float4 b = *(const float4*)(rp + 256 + lane * 4);
    float sum = a.x + a.y + a.z + a.w + b.x + b.y + b.z + b.w;
    float sq  = a.x*a.x + a.y*a.y + a.z*a.z + a.w*a.w
              + b.x*b.x + b.y*b.y + b.z*b.z + b.w*b.w;
    #pragma unroll
    for (int d = 1; d < 64; d <<= 1) {
        sum += __shfl_xor(sum, d, 64);
        sq  += __shfl_xor(sq,  d, 64);
    }
    float mu = sum * (1.0f / HSZ_);
    float varv = fmaxf(sq * (1.0f / HSZ_) - mu * mu, 0.f);
    float rs = rsqrtf(varv + 1e-5f);
    bf16* op = out + (size_t)row * HSZ_;
    int c0 = lane * 4;
    float va[4] = {a.x, a.y, a.z, a.w}, vb[4] = {b.x, b.y, b.z, b.w};
    #pragma unroll
    for (int k = 0; k < 4; k++) {
        op[c0 + k]       = (bf16)(((va[k] - mu) * rs) * sc[c0 + k] + bi[c0 + k]);
        op[c0 + 256 + k] = (bf16)(((vb[k] - mu) * rs) * sc[c0 + 256 + k] + bi[c0 + 256 + k]);
    }
}

// ---------------------------------------------------------------------------
__global__ __launch_bounds__(256) void write_out(const bf16* __restrict__ x,
                                                 float* __restrict__ out) {
    size_t tid = (size_t)blockIdx.x * 256 + threadIdx.x;
    if (tid < (size_t)B_ * HSZ_) {
        int b = (int)(tid >> 9), c = (int)(tid & 511);
        out[tid] = (float)x[((size_t)(b * N_ + E_)) * HSZ_ + c];
    } else if (tid < (size_t)B_ * HSZ_ + (size_t)B_ * N_ * HSZ_) {
        out[tid] = (float)x[tid - B_ * HSZ_];
    } else {
        out[tid] = 1.0f;
    }
}

// ---------------------------------------------------------------------------
extern "C" void kernel_launch(void* const* d_in, const int* in_sizes, int n_in,
                              void* d_out, int out_size, void* d_ws, size_t ws_size,
                              hipStream_t stream) {
    const float* ents = (const float*)d_in[0];
    const int*   rels = (const int*)d_in[1];
    const int*   adj  = (const int*)d_in[2];
    const float* renc = (const float*)d_in[3];
    const float* Wq   = (const float*)d_in[4];
    const float* Wk   = (const float*)d_in[5];
    const float* Wv   = (const float*)d_in[6];
    const float* l1w  = (const float*)d_in[7];
    const float* l1b  = (const float*)d_in[8];
    const float* l2w  = (const float*)d_in[9];
    const float* l2b  = (const float*)d_in[10];
    const float* ln1s = (const float*)d_in[11];
    const float* ln1b = (const float*)d_in[12];
    const float* ln2s = (const float*)d_in[13];
    const float* ln2b = (const float*)d_in[14];
    const float* pa   = (const float*)d_in[15];

    char* ws = (char*)d_ws;
    size_t o = 0;
    auto alloc = [&](size_t bytes) { void* p = ws + o; o += bytes; return p; };
    bf16*     WqT    = (bf16*)alloc(1048576);
    bf16*     WkT    = (bf16*)alloc(1048576);
    bf16*     WvT    = (bf16*)alloc(1048576);
    bf16*     L1T    = (bf16*)alloc(4194304);
    bf16*     L2T    = (bf16*)alloc(4194304);
    unsigned* adjw   = (unsigned*)alloc(2097152);
    bf16*     xb     = (bf16*)alloc(16777216);
    bf16*     Qb     = (bf16*)alloc(16777216);
    bf16*     Kb     = (bf16*)alloc(16777216);
    bf16*     Vt     = (bf16*)alloc(16777216);
    bf16*     tb     = (bf16*)alloc(16777216);
    bf16*     hb     = (bf16*)alloc(67108864);
    float*    f32buf = (float*)alloc(33554432);
    if (o > ws_size) return;

    dim3 t32(32, 8);
    for (int j = 0; j < 2; j++) {
        transpose_f32_bf16<<<dim3(16, 16), t32, 0, stream>>>(Wq  + j * 262144,  WqT + j * 262144, 512, 512);
        transpose_f32_bf16<<<dim3(16, 16), t32, 0, stream>>>(Wk  + j * 262144,  WkT + j * 262144, 512, 512);
        transpose_f32_bf16<<<dim3(16, 16), t32, 0, stream>>>(Wv  + j * 262144,  WvT + j * 262144, 512, 512);
        transpose_f32_bf16<<<dim3(64, 16), t32, 0, stream>>>(l1w + j * 1048576, L1T + j * 1048576, 512, 2048);
        transpose_f32_bf16<<<dim3(16, 64), t32, 0, stream>>>(l2w + j * 1048576, L2T + j * 1048576, 2048, 512);
    }
    pack_adj<<<65536, 256, 0, stream>>>(adj, adjw);
    build_x<<<4096, 256, 0, stream>>>(ents, rels, renc, xb);

    for (int j = 0; j < 2; j++) {
        gemm_bt<0><<<dim3(4, 128), 256, 0, stream>>>(xb, WqT + j * 262144, nullptr, nullptr, nullptr, Qb, nullptr, 512, 512);
        gemm_bt<0><<<dim3(4, 128), 256, 0, stream>>>(xb, WkT + j * 262144, nullptr, nullptr, nullptr, Kb, nullptr, 512, 512);
        gemm_bt<1><<<dim3(4, 128), 256, 0, stream>>>(xb, WvT + j * 262144, nullptr, nullptr, nullptr, Vt, nullptr, 512, 512);
        attn_fused<<<1024, 256, 0, stream>>>(Qb, Kb, Vt, adjw, xb, f32buf);
        lnorm_k<<<16384, 64, 0, stream>>>(f32buf, ln1s + j * 512, ln1b + j * 512, tb);
        gemm_bt<2><<<dim3(16, 128), 256, 0, stream>>>(tb, L1T + j * 1048576, l1b + j * 2048, pa + j * 2048, nullptr, hb, nullptr, 2048, 512);
        gemm_bt<3><<<dim3(4, 128), 256, 0, stream>>>(hb, L2T + j * 1048576, l2b + j * 512, nullptr, tb, nullptr, f32buf, 512, 2048);
        lnorm_k<<<16384, 64, 0, stream>>>(f32buf, ln2s + j * 512, ln2b + j * 512, xb);
    }
    write_out<<<32864, 256, 0, stream>>>(xb, (float*)d_out);
}

// Round 15
// 832.156 us; speedup vs baseline: 1.3953x; 1.0138x over previous
//
#include <hip/hip_runtime.h>
#include <hip/hip_bf16.h>

typedef __bf16 bf16;
typedef __attribute__((ext_vector_type(8))) bf16 bf16x8;
typedef __attribute__((ext_vector_type(4))) float f32x4;

constexpr int B_   = 16;
constexpr int E_   = 400;
constexpr int R_   = 624;
constexpr int N_   = 1024;
constexpr int HSZ_ = 512;
constexpr int DFF_ = 2048;
constexpr int M_   = B_ * N_;

// ---------------------------------------------------------------------------
__global__ __launch_bounds__(256) void transpose_f32_bf16(const float* __restrict__ in,
                                                          bf16* __restrict__ out,
                                                          int rows, int cols) {
    __shared__ float tile[32][33];
    int c0 = blockIdx.x * 32, r0 = blockIdx.y * 32;
    int tx = threadIdx.x, ty = threadIdx.y;   // 32 x 8
    #pragma unroll
    for (int i = 0; i < 32; i += 8)
        tile[ty + i][tx] = in[(size_t)(r0 + ty + i) * cols + (c0 + tx)];
    __syncthreads();
    #pragma unroll
    for (int i = 0; i < 32; i += 8)
        out[(size_t)(c0 + ty + i) * rows + (r0 + tx)] = (bf16)tile[tx][ty + i];
}

// ---------------------------------------------------------------------------
__global__ __launch_bounds__(256) void pack_adj(const int* __restrict__ adj,
                                                unsigned* __restrict__ adjw) {
    int gid  = blockIdx.x * 4 + (threadIdx.x >> 6);
    int lane = threadIdx.x & 63;
    int w64  = gid & 15;
    int bn   = gid >> 4;
    int v = adj[(size_t)bn * N_ + w64 * 64 + lane];
    unsigned long long mask = __ballot(v != 0);
    if (lane == 0)  adjw[bn * 32 + w64 * 2]     = (unsigned)mask;
    if (lane == 32) adjw[bn * 32 + w64 * 2 + 1] = (unsigned)(mask >> 32);
}

// ---------------------------------------------------------------------------
__global__ __launch_bounds__(256) void build_x(const float* __restrict__ ents,
                                               const int* __restrict__ rels,
                                               const float* __restrict__ renc,
                                               bf16* __restrict__ x) {
    int idx  = blockIdx.x * 256 + threadIdx.x;
    int col8 = (idx & 63) * 8;
    int row  = idx >> 6;
    int b = row >> 10, n = row & 1023;
    const float* src;
    if (n < E_) src = ents + ((size_t)(b * E_ + n)) * HSZ_ + col8;
    else {
        int rt = rels[b * R_ + (n - E_)];
        src = renc + (size_t)rt * HSZ_ + col8;
    }
    float4 a = *(const float4*)src;
    float4 c = *(const float4*)(src + 4);
    bf16x8 v;
    v[0] = (bf16)a.x; v[1] = (bf16)a.y; v[2] = (bf16)a.z; v[3] = (bf16)a.w;
    v[4] = (bf16)c.x; v[5] = (bf16)c.y; v[6] = (bf16)c.z; v[7] = (bf16)c.w;
    *(bf16x8*)(x + (size_t)row * HSZ_ + col8) = v;
}

// ---------------------------------------------------------------------------
// GEMM (R10-proven): C(M x Nn) = A(M x Kk) @ Bt(Nn x Kk)^T, 128x128 tile,
// 4 waves (2x2), 4x4 16x16x32 MFMA tiles/wave, padded LDS staging.
template <int MODE>
__global__ __launch_bounds__(256) void gemm_bt(const bf16* __restrict__ A,
                                               const bf16* __restrict__ Bt,
                                               const float* __restrict__ biasF,
                                               const float* __restrict__ alphaF,
                                               const bf16* __restrict__ extraB,
                                               bf16* __restrict__ outB,
                                               float* __restrict__ outF,
                                               int Nn, int Kk) {
    __shared__ bf16 As[128][72];
    __shared__ bf16 Bs[128][72];
    int n0 = blockIdx.x * 128, m0 = blockIdx.y * 128;
    int t = threadIdx.x;
    int w = t >> 6, lane = t & 63, r = lane & 15, quad = lane >> 4;
    int wm = w >> 1, wn = w & 1;
    f32x4 acc[4][4];
    #pragma unroll
    for (int mt = 0; mt < 4; mt++)
        #pragma unroll
        for (int nt = 0; nt < 4; nt++) acc[mt][nt] = (f32x4){0.f, 0.f, 0.f, 0.f};

    for (int k0 = 0; k0 < Kk; k0 += 64) {
        #pragma unroll
        for (int i = 0; i < 4; i++) {
            int v = t + i * 256;
            int row = v >> 3, c8 = (v & 7) * 8;
            *(uint4*)&As[row][c8] = *(const uint4*)&A[(size_t)(m0 + row) * Kk + k0 + c8];
            *(uint4*)&Bs[row][c8] = *(const uint4*)&Bt[(size_t)(n0 + row) * Kk + k0 + c8];
        }
        __syncthreads();
        #pragma unroll
        for (int kk = 0; kk < 64; kk += 32) {
            bf16x8 af[4], bfr[4];
            #pragma unroll
            for (int mt = 0; mt < 4; mt++)
                af[mt] = *(const bf16x8*)&As[wm * 64 + mt * 16 + r][kk + quad * 8];
            #pragma unroll
            for (int nt = 0; nt < 4; nt++)
                bfr[nt] = *(const bf16x8*)&Bs[wn * 64 + nt * 16 + r][kk + quad * 8];
            #pragma unroll
            for (int mt = 0; mt < 4; mt++)
                #pragma unroll
                for (int nt = 0; nt < 4; nt++)
                    acc[mt][nt] = __builtin_amdgcn_mfma_f32_16x16x32_bf16(af[mt], bfr[nt], acc[mt][nt], 0, 0, 0);
        }
        __syncthreads();
    }
    #pragma unroll
    for (int mt = 0; mt < 4; mt++) {
        #pragma unroll
        for (int nt = 0; nt < 4; nt++) {
            #pragma unroll
            for (int i = 0; i < 4; i++) {
                int rg = m0 + wm * 64 + mt * 16 + quad * 4 + i;
                int cg = n0 + wn * 64 + nt * 16 + r;
                float v = acc[mt][nt][i];
                if (MODE == 0) {
                    outB[(size_t)rg * Nn + cg] = (bf16)v;
                } else if (MODE == 1) {
                    int bb = rg >> 10, n = rg & 1023;
                    outB[(size_t)(bb * HSZ_ + cg) * N_ + n] = (bf16)v;
                } else if (MODE == 2) {
                    v += biasF[cg];
                    float a = alphaF[cg];
                    v = v > 0.f ? v : a * v;
                    outB[(size_t)rg * Nn + cg] = (bf16)v;
                } else {
                    v += biasF[cg] + (float)extraB[(size_t)rg * Nn + cg];
                    outF[(size_t)rg * Nn + cg] = v;
                }
            }
        }
    }
}

// ---------------------------------------------------------------------------
// Fused MFMA attention v7: reuse-blocked (64 q-rows/block), PADDED plain-load
// K/V staging (R14's glds tiles had 16-way bank conflicts: stride 256B/128B
// -> all 16 r-lanes on one bank, 4.2e7 conflict cycles), XCD-swizzled grid
// (R14 dropped it: FETCH 37->148 MB). Wave w owns q-rows n0+w*16 end-to-end.
__global__ __launch_bounds__(256) void attn_fused(const bf16* __restrict__ Q,
                                                  const bf16* __restrict__ K,
                                                  const bf16* __restrict__ Vt,
                                                  const unsigned* __restrict__ adjw,
                                                  const bf16* __restrict__ xb,
                                                  float* __restrict__ tpre) {
    int blk = blockIdx.x;
    // blk = gr + 8*(qb + 16*gq): group g = gq*8+gr = b*4+h -> all 16 q-blocks
    // of a group share blk%8 (same XCD on round-robin dispatch).
    int gr = blk & 7;
    int qb = (blk >> 3) & 15;
    int gq = blk >> 7;
    int g = gq * 8 + gr;
    int b = g >> 2, h = g & 3;

    int tid = threadIdx.x;
    int w = tid >> 6, lane = tid & 63;
    int r = lane & 15, quad = lane >> 4;
    int n0 = qb * 64 + w * 16;       // this wave's 16 q-rows

    __shared__ bf16 Ks[64][136];     // [key][dim], +8 pad -> 2-way (free)
    __shared__ bf16 Vs[128][72];     // [dim][key], +8 pad -> 2-way (free)
    __shared__ bf16 plds[4][16][68]; // per-wave P tile, padded

    bf16x8 qf[4];
    const bf16* qbase = Q + ((size_t)(b * N_ + n0 + r)) * HSZ_ + h * 128;
    #pragma unroll
    for (int kc = 0; kc < 4; kc++) qf[kc] = *(const bf16x8*)(qbase + kc * 32 + quad * 8);

    f32x4 accv[8];
    #pragma unroll
    for (int dt = 0; dt < 8; dt++) accv[dt] = (f32x4){0.f, 0.f, 0.f, 0.f};
    float tl[4] = {0.f, 0.f, 0.f, 0.f};
    const float scale = 0.04419417382415922f;   // 1/sqrt(512)
    const float SHIFT = 12.0f;

    for (int it = 0; it < 16; it++) {
        int key0 = it * 64;
        __syncthreads();   // all waves done reading Ks/Vs from prev iter
        // stage K tile 64x128: 1024 uint4, 4/thread
        #pragma unroll
        for (int i = 0; i < 4; i++) {
            int e = tid + i * 256;
            int krow = e >> 4, kc8 = (e & 15) * 8;
            *(uint4*)&Ks[krow][kc8] =
                *(const uint4*)&K[((size_t)(b * N_ + key0 + krow)) * HSZ_ + h * 128 + kc8];
        }
        // stage V tile 128x64: 1024 uint4, 4/thread
        #pragma unroll
        for (int i = 0; i < 4; i++) {
            int e = tid + i * 256;
            int vrow = e >> 3, vc8 = (e & 7) * 8;
            *(uint4*)&Vs[vrow][vc8] =
                *(const uint4*)&Vt[((size_t)(b * HSZ_ + h * 128 + vrow)) * N_ + key0 + vc8];
        }
        __syncthreads();   // staging visible

        // QK^T: 4 groups of 16 keys from LDS
        f32x4 cg[4];
        #pragma unroll
        for (int gk = 0; gk < 4; gk++) cg[gk] = (f32x4){0.f, 0.f, 0.f, 0.f};
        #pragma unroll
        for (int gk = 0; gk < 4; gk++)
            #pragma unroll
            for (int kc = 0; kc < 4; kc++) {
                bf16x8 kf = *(const bf16x8*)&Ks[gk * 16 + r][kc * 32 + quad * 8];
                cg[gk] = __builtin_amdgcn_mfma_f32_16x16x32_bf16(qf[kc], kf, cg[gk], 0, 0, 0);
            }
        // mask + exp -> plds + tl
        #pragma unroll
        for (int i = 0; i < 4; i++) {
            int row_g = n0 + quad * 4 + i;
            const unsigned* aw = &adjw[((size_t)(b << 10) + row_g) * 32 + it * 2];
            unsigned wb0 = aw[0], wb1 = aw[1];
            float p0 = ((wb0 >> r) & 1u)        ? __expf(cg[0][i] * scale - SHIFT) : 0.f;
            float p1 = ((wb0 >> (16 + r)) & 1u) ? __expf(cg[1][i] * scale - SHIFT) : 0.f;
            float p2 = ((wb1 >> r) & 1u)        ? __expf(cg[2][i] * scale - SHIFT) : 0.f;
            float p3 = ((wb1 >> (16 + r)) & 1u) ? __expf(cg[3][i] * scale - SHIFT) : 0.f;
            tl[i] += p0 + p1 + p2 + p3;
            plds[w][quad * 4 + i][r]      = (bf16)p0;
            plds[w][quad * 4 + i][16 + r] = (bf16)p1;
            plds[w][quad * 4 + i][32 + r] = (bf16)p2;
            plds[w][quad * 4 + i][48 + r] = (bf16)p3;
        }
        __syncthreads();   // P visible (block barrier: proven-safe path)

        // PV: P (A-op, 64 keys in 2 k-chunks) x Vs for all 128 dims
        bf16x8 pf0 = *(const bf16x8*)&plds[w][r][quad * 8];
        bf16x8 pf1 = *(const bf16x8*)&plds[w][r][32 + quad * 8];
        #pragma unroll
        for (int dt = 0; dt < 8; dt++) {
            bf16x8 v0 = *(const bf16x8*)&Vs[dt * 16 + r][quad * 8];
            bf16x8 v1 = *(const bf16x8*)&Vs[dt * 16 + r][32 + quad * 8];
            accv[dt] = __builtin_amdgcn_mfma_f32_16x16x32_bf16(pf0, v0, accv[dt], 0, 0, 0);
            accv[dt] = __builtin_amdgcn_mfma_f32_16x16x32_bf16(pf1, v1, accv[dt], 0, 0, 0);
        }
    }
    // per-wave epilogue
    #pragma unroll
    for (int i = 0; i < 4; i++) {
        float l = tl[i];
        #pragma unroll
        for (int d = 1; d < 16; d <<= 1) l += __shfl_xor(l, d, 64);
        float inv_l = 1.0f / fmaxf(l, 1e-30f);
        #pragma unroll
        for (int dt = 0; dt < 8; dt++) {
            int row = n0 + quad * 4 + i;
            int col = h * 128 + dt * 16 + r;
            size_t idx = ((size_t)(b * N_ + row)) * HSZ_ + col;
            tpre[idx] = accv[dt][i] * inv_l + (float)xb[idx];
        }
    }
}

// ---------------------------------------------------------------------------
__global__ __launch_bounds__(64) void lnorm_k(const float* __restrict__ in,
                                              const float* __restrict__ sc,
                                              const float* __restrict__ bi,
                                              bf16* __restrict__ out) {
    int row = blockIdx.x;
    int lane = threadIdx.x;
    const float* rp = in + (size_t)row * HSZ_;
    float4 a = *(const float4*)(rp + lane * 4);
    float4 b = *(const float4*)(rp + 256 + lane * 4);
    float sum = a.x + a.y + a.z + a.w + b.x + b.y + b.z + b.w;
    float sq  = a.x*a.x + a.y*a.y + a.z*a.z + a.w*a.w
              + b.x*b.x + b.y*b.y + b.z*b.z + b.w*b.w;
    #pragma unroll
    for (int d = 1; d < 64; d <<= 1) {
        sum += __shfl_xor(sum, d, 64);
        sq  += __shfl_xor(sq,  d, 64);
    }
    float mu = sum * (1.0f / HSZ_);
    float varv = fmaxf(sq * (1.0f / HSZ_) - mu * mu, 0.f);
    float rs = rsqrtf(varv + 1e-5f);
    bf16* op = out + (size_t)row * HSZ_;
    int c0 = lane * 4;
    float va[4] = {a.x, a.y, a.z, a.w}, vb[4] = {b.x, b.y, b.z, b.w};
    #pragma unroll
    for (int k = 0; k < 4; k++) {
        op[c0 + k]       = (bf16)(((va[k] - mu) * rs) * sc[c0 + k] + bi[c0 + k]);
        op[c0 + 256 + k] = (bf16)(((vb[k] - mu) * rs) * sc[c0 + 256 + k] + bi[c0 + 256 + k]);
    }
}

// ---------------------------------------------------------------------------
__global__ __launch_bounds__(256) void write_out(const bf16* __restrict__ x,
                                                 float* __restrict__ out) {
    size_t tid = (size_t)blockIdx.x * 256 + threadIdx.x;
    if (tid < (size_t)B_ * HSZ_) {
        int b = (int)(tid >> 9), c = (int)(tid & 511);
        out[tid] = (float)x[((size_t)(b * N_ + E_)) * HSZ_ + c];
    } else if (tid < (size_t)B_ * HSZ_ + (size_t)B_ * N_ * HSZ_) {
        out[tid] = (float)x[tid - B_ * HSZ_];
    } else {
        out[tid] = 1.0f;
    }
}

// ---------------------------------------------------------------------------
extern "C" void kernel_launch(void* const* d_in, const int* in_sizes, int n_in,
                              void* d_out, int out_size, void* d_ws, size_t ws_size,
                              hipStream_t stream) {
    const float* ents = (const float*)d_in[0];
    const int*   rels = (const int*)d_in[1];
    const int*   adj  = (const int*)d_in[2];
    const float* renc = (const float*)d_in[3];
    const float* Wq   = (const float*)d_in[4];
    const float* Wk   = (const float*)d_in[5];
    const float* Wv   = (const float*)d_in[6];
    const float* l1w  = (const float*)d_in[7];
    const float* l1b  = (const float*)d_in[8];
    const float* l2w  = (const float*)d_in[9];
    const float* l2b  = (const float*)d_in[10];
    const float* ln1s = (const float*)d_in[11];
    const float* ln1b = (const float*)d_in[12];
    const float* ln2s = (const float*)d_in[13];
    const float* ln2b = (const float*)d_in[14];
    const float* pa   = (const float*)d_in[15];

    char* ws = (char*)d_ws;
    size_t o = 0;
    auto alloc = [&](size_t bytes) { void* p = ws + o; o += bytes; return p; };
    bf16*     WqT    = (bf16*)alloc(1048576);
    bf16*     WkT    = (bf16*)alloc(1048576);
    bf16*     WvT    = (bf16*)alloc(1048576);
    bf16*     L1T    = (bf16*)alloc(4194304);
    bf16*     L2T    = (bf16*)alloc(4194304);
    unsigned* adjw   = (unsigned*)alloc(2097152);
    bf16*     xb     = (bf16*)alloc(16777216);
    bf16*     Qb     = (bf16*)alloc(16777216);
    bf16*     Kb     = (bf16*)alloc(16777216);
    bf16*     Vt     = (bf16*)alloc(16777216);
    bf16*     tb     = (bf16*)alloc(16777216);
    bf16*     hb     = (bf16*)alloc(67108864);
    float*    f32buf = (float*)alloc(33554432);
    if (o > ws_size) return;

    dim3 t32(32, 8);
    for (int j = 0; j < 2; j++) {
        transpose_f32_bf16<<<dim3(16, 16), t32, 0, stream>>>(Wq  + j * 262144,  WqT + j * 262144, 512, 512);
        transpose_f32_bf16<<<dim3(16, 16), t32, 0, stream>>>(Wk  + j * 262144,  WkT + j * 262144, 512, 512);
        transpose_f32_bf16<<<dim3(16, 16), t32, 0, stream>>>(Wv  + j * 262144,  WvT + j * 262144, 512, 512);
        transpose_f32_bf16<<<dim3(64, 16), t32, 0, stream>>>(l1w + j * 1048576, L1T + j * 1048576, 512, 2048);
        transpose_f32_bf16<<<dim3(16, 64), t32, 0, stream>>>(l2w + j * 1048576, L2T + j * 1048576, 2048, 512);
    }
    pack_adj<<<65536, 256, 0, stream>>>(adj, adjw);
    build_x<<<4096, 256, 0, stream>>>(ents, rels, renc, xb);

    for (int j = 0; j < 2; j++) {
        gemm_bt<0><<<dim3(4, 128), 256, 0, stream>>>(xb, WqT + j * 262144, nullptr, nullptr, nullptr, Qb, nullptr, 512, 512);
        gemm_bt<0><<<dim3(4, 128), 256, 0, stream>>>(xb, WkT + j * 262144, nullptr, nullptr, nullptr, Kb, nullptr, 512, 512);
        gemm_bt<1><<<dim3(4, 128), 256, 0, stream>>>(xb, WvT + j * 262144, nullptr, nullptr, nullptr, Vt, nullptr, 512, 512);
        attn_fused<<<1024, 256, 0, stream>>>(Qb, Kb, Vt, adjw, xb, f32buf);
        lnorm_k<<<16384, 64, 0, stream>>>(f32buf, ln1s + j * 512, ln1b + j * 512, tb);
        gemm_bt<2><<<dim3(16, 128), 256, 0, stream>>>(tb, L1T + j * 1048576, l1b + j * 2048, pa + j * 2048, nullptr, hb, nullptr, 2048, 512);
        gemm_bt<3><<<dim3(4, 128), 256, 0, stream>>>(hb, L2T + j * 1048576, l2b + j * 512, nullptr, tb, nullptr, f32buf, 512, 2048);
        lnorm_k<<<16384, 64, 0, stream>>>(f32buf, ln2s + j * 512, ln2b + j * 512, xb);
    }
    write_out<<<32864, 256, 0, stream>>>(xb, (float*)d_out);
}